// Round 10
// baseline (53.564 us; speedup 1.0000x reference)
//
#include <hip/hip_runtime.h>
#include <hip/hip_bf16.h>

// MSTGCN head — fused bf16-MFMA implementation (round 10 = round 9 + bugfix).
// cheb = [I,-I,I] (identity adjacency) => graph conv = per-(b,n) GEMM with
// te = theta0 - theta1 + theta2.
//
// Decomposition: 16384 (b,n) pairs. Wave = 4 pairs = 48 rows = 3 M-tiles of 16.
// Block = 4 waves = 16 pairs. Grid = 1024.
//
// Round-10 fix: round-9's W2 stage index expression evaluated to 2*sl (W1
// frags) instead of FR_W2+sl -> GEMM2 used wrong weights, absmax 8.9.
// Structure unchanged:
//  - 24KB phase-staged weight buffer (6 phases: W1S,W1R,TW0,W2,TW1,FW),
//    LDS = 24KB tiles + 24KB WB = 48KB -> 3 blocks/CU = 12 waves/CU.
//  - single-acc two-pass GEMMs (48 acc regs) to fit the 84/84 arch/acc split
//    at __launch_bounds__(256,3) (dual-acc 96 spilled at this bound, round 6).
//  - W2/FW stages issued before LN0/LN1 so their latency hides under LN math.

typedef __attribute__((ext_vector_type(8))) short bf16x8;
typedef __attribute__((ext_vector_type(4))) float f32x4;

#define FR_W1   0     // 32 frags: ks(4)*8 + nt(8)   K=128,N=128 [te0|rw0T]
#define FR_TW0  32    // 24 frags: dt*8 + ks(2)*4 + nt(4)
#define FR_W2   56    // 16 frags: ks(2)*8 + nt(8)   K=64,N=128 [te1|rw1T]
#define FR_TW1  72    // 24 frags
#define FR_FW   96    // 24 frags: ks(24), N=16 (cols 12..15 zero)
#define N_FRAGS 120

__device__ __forceinline__ unsigned short f2bf(float f) {
    unsigned u = __builtin_bit_cast(unsigned, f);
    return (unsigned short)((u + 0x7FFFu + ((u >> 16) & 1u)) >> 16);
}

__device__ __forceinline__ unsigned short hcvt(float f) {
    union { __hip_bfloat16 h; unsigned short u; } cv;
    cv.h = __float2bfloat16(f);
    return cv.u;
}

__global__ void prep(const float* __restrict__ th0, const float* __restrict__ tw0,
                     const float* __restrict__ rw0, const float* __restrict__ th1,
                     const float* __restrict__ tw1, const float* __restrict__ rw1,
                     const float* __restrict__ fw,  short* __restrict__ wsb)
{
    int e = blockIdx.x * 256 + threadIdx.x;     // (frag, lane, i)
    if (e >= N_FRAGS * 512) return;
    int frag = e >> 9;
    int l    = (e >> 3) & 63;
    int i    = e & 7;
    int kif  = ((l >> 4) << 3) + i;             // k within 32-chunk
    int nif  = l & 15;
    float val = 0.f;
    if (frag < 32) {                                       // W1
        int ks = frag >> 3, nt = frag & 7;
        int k = ks * 32 + kif, n = nt * 16 + nif;
        if (n < 64) val = th0[k*64+n] - th0[8192 + k*64+n] + th0[16384 + k*64+n];
        else        val = rw0[(n - 64) * 128 + k];
    } else if (frag < 56) {                                // TW0
        int q = frag - 32; int dt = q >> 3, ks = (q >> 2) & 1, nt = q & 3;
        int c = ks * 32 + kif, o = nt * 16 + nif;
        val = tw0[o * 192 + c * 3 + dt];
    } else if (frag < 72) {                                // W2
        int q = frag - 56; int ks = q >> 3, nt = q & 7;
        int k = ks * 32 + kif, n = nt * 16 + nif;
        if (n < 64) val = th1[k*64+n] - th1[4096 + k*64+n] + th1[8192 + k*64+n];
        else        val = rw1[(n - 64) * 64 + k];
    } else if (frag < 96) {                                // TW1
        int q = frag - 72; int dt = q >> 3, ks = (q >> 2) & 1, nt = q & 3;
        int c = ks * 32 + kif, o = nt * 16 + nif;
        val = tw1[o * 192 + c * 3 + dt];
    } else {                                               // FW
        int ks = frag - 96; int k = ks * 32 + kif; int po = nif;
        val = (po < 12) ? fw[po * 768 + k] : 0.f;
    }
    wsb[e] = (short)f2bf(val);
}

// LDS layout:
//   [0 .. 24575]   : 4 per-wave 48x64 bf16 s/y tiles (6 KB each, XOR-swizzled)
//   [24576..49151] : 24 KB weight buffer (one phase at a time)
#define LDS_SY(w)  (LDS + (w) * 6144)
#define LDS_WB     (LDS + 24576)

__global__ __launch_bounds__(256, 3) void mstgcn_mfma(
    const float* __restrict__ x,   const short* __restrict__ wsb,
    const float* __restrict__ tb0, const float* __restrict__ rb0,
    const float* __restrict__ lg0, const float* __restrict__ lb0,
    const float* __restrict__ tb1, const float* __restrict__ rb1,
    const float* __restrict__ lg1, const float* __restrict__ lb1,
    const float* __restrict__ fb,  float* __restrict__ out)
{
    __shared__ __align__(16) char LDS[49152];

    const int lane = threadIdx.x & 63;
    const int wave = threadIdx.x >> 6;
    const int l15  = lane & 15;
    const int l4   = lane >> 4;
    const int pair0 = blockIdx.x * 16 + wave * 4;

    char* syB = LDS_SY(wave);
    char* WB  = LDS_WB;

    // WB readers/writers: slot = 1KB fragment, lane-consecutive 16B
    auto ldwb = [&](int slot) -> bf16x8 {
        return *(const bf16x8*)(WB + slot * 1024 + lane * 16);
    };
    auto stage1 = [&](int slot, int fg) {
        *(bf16x8*)(WB + slot * 1024 + lane * 16) =
            *(const bf16x8*)(wsb + fg * 512 + lane * 8);
    };

    // A-row decode (rows 0..47 within wave; row -> (pair, t))
    int tA[3];
    long gbase[3];
    #pragma unroll
    for (int mt = 0; mt < 3; ++mt) {
        int r = mt * 16 + l15;
        int p = r / 12;
        tA[mt]   = r - p * 12;
        gbase[mt] = ((long)(pair0 + p) * 12 + tA[mt]) * 128;
    }

    // ============ stage W1S (16 frags: ks*8+nt, nt<4) ∥ X->aC prefetch =======
    #pragma unroll
    for (int i = 0; i < 4; ++i) {
        int sl = i * 4 + wave;
        stage1(sl, ((sl >> 2) << 3) + (sl & 3));
    }
    bf16x8 aC[12];
    #pragma unroll
    for (int ks = 0; ks < 4; ++ks)
        #pragma unroll
        for (int mt = 0; mt < 3; ++mt) {
            const float* p = x + gbase[mt] + ks * 32 + l4 * 8;
            float v[8];
            *(float4*)(v)     = *(const float4*)(p);
            *(float4*)(v + 4) = *(const float4*)(p + 4);
            bf16x8 af;
            #pragma unroll
            for (int j = 0; j < 8; ++j) af[j] = (short)hcvt(v[j]);
            aC[ks * 3 + mt] = af;
        }
    __syncthreads();                                       // B1: W1S resident

    f32x4 acc[3][4];
    #pragma unroll
    for (int mt = 0; mt < 3; ++mt)
        #pragma unroll
        for (int nt = 0; nt < 4; ++nt) acc[mt][nt] = (f32x4)0.f;

    // ============ GEMM1 pass S: X @ te0 ============
    #pragma unroll
    for (int ks = 0; ks < 4; ++ks)
        #pragma unroll
        for (int nt = 0; nt < 4; ++nt) {
            bf16x8 b = ldwb(ks * 4 + nt);
            #pragma unroll
            for (int mt = 0; mt < 3; ++mt)
                acc[mt][nt] = __builtin_amdgcn_mfma_f32_16x16x32_bf16(aC[ks * 3 + mt], b, acc[mt][nt], 0, 0, 0);
        }
    // s = relu(acc) -> own tile (swizzled bf16)
    #pragma unroll
    for (int mt = 0; mt < 3; ++mt)
        #pragma unroll
        for (int j = 0; j < 4; ++j) {
            int row = mt * 16 + l4 * 4 + j;
            int sw  = (row & 7) << 4;
            #pragma unroll
            for (int nt = 0; nt < 4; ++nt) {
                int col = nt * 16 + l15;
                *(short*)(syB + row * 128 + ((col * 2) ^ sw)) =
                    (short)hcvt(fmaxf(acc[mt][nt][j], 0.f));
            }
        }
    __syncthreads();                                       // B2: done reading W1S

    // ============ stage W1R (frags ks*8+4+nt) ============
    #pragma unroll
    for (int i = 0; i < 4; ++i) {
        int sl = i * 4 + wave;
        stage1(sl, ((sl >> 2) << 3) + 4 + (sl & 3));
    }
    __syncthreads();                                       // B3: W1R resident

    // ============ GEMM1 pass R: X @ rw0T ============
    #pragma unroll
    for (int mt = 0; mt < 3; ++mt)
        #pragma unroll
        for (int nt = 0; nt < 4; ++nt) acc[mt][nt] = (f32x4)0.f;
    #pragma unroll
    for (int ks = 0; ks < 4; ++ks)
        #pragma unroll
        for (int nt = 0; nt < 4; ++nt) {
            bf16x8 b = ldwb(ks * 4 + nt);
            #pragma unroll
            for (int mt = 0; mt < 3; ++mt)
                acc[mt][nt] = __builtin_amdgcn_mfma_f32_16x16x32_bf16(aC[ks * 3 + mt], b, acc[mt][nt], 0, 0, 0);
        }
    __syncthreads();                                       // B4: done reading W1R

    // ============ stage TW0 (24 frags) ============
    #pragma unroll
    for (int i = 0; i < 6; ++i) {
        int sl = i * 4 + wave;
        stage1(sl, FR_TW0 + sl);
    }
    __syncthreads();                                       // B5: TW0 resident

    // ============ tconv0 (3 shifted GEMMs) += acc ============
    #pragma unroll
    for (int dt = 0; dt < 3; ++dt) {
        #pragma unroll
        for (int ks = 0; ks < 2; ++ks) {
            bf16x8 a[3];
            #pragma unroll
            for (int mt = 0; mt < 3; ++mt) {
                int ts    = tA[mt] + dt - 1;
                bool ok   = (ts >= 0) && (ts < 12);
                int srow  = ok ? (mt * 16 + l15 + dt - 1) : (mt * 16 + l15);
                int kb    = (ks * 32 + l4 * 8) * 2;
                bf16x8 av = *(const bf16x8*)(syB + srow * 128 + (kb ^ ((srow & 7) << 4)));
                a[mt] = ok ? av : (bf16x8)(short)0;
            }
            #pragma unroll
            for (int nt = 0; nt < 4; ++nt) {
                bf16x8 b = ldwb(dt * 8 + ks * 4 + nt);
                #pragma unroll
                for (int mt = 0; mt < 3; ++mt)
                    acc[mt][nt] = __builtin_amdgcn_mfma_f32_16x16x32_bf16(a[mt], b, acc[mt][nt], 0, 0, 0);
            }
        }
    }
    __syncthreads();                                       // B6: done reading TW0

    // ============ stage W2 (16 frags) — latency hidden under LN0 ============
    #pragma unroll
    for (int i = 0; i < 4; ++i) {
        int sl = i * 4 + wave;
        stage1(sl, FR_W2 + sl);
    }

    // ============ bias + relu + LN0 -> y1 into own tile ============
    {
        float bv[4], lgv[4], lbv[4];
        #pragma unroll
        for (int nt = 0; nt < 4; ++nt) {
            int col = nt * 16 + l15;
            bv[nt]  = rb0[col] + tb0[col];
            lgv[nt] = lg0[col];
            lbv[nt] = lb0[col];
        }
        #pragma unroll
        for (int mt = 0; mt < 3; ++mt)
            #pragma unroll
            for (int j = 0; j < 4; ++j) {
                float v[4], sm = 0.f, sq = 0.f;
                #pragma unroll
                for (int nt = 0; nt < 4; ++nt) {
                    v[nt] = fmaxf(acc[mt][nt][j] + bv[nt], 0.f);
                    sm += v[nt]; sq += v[nt] * v[nt];
                }
                #pragma unroll
                for (int m = 8; m; m >>= 1) {
                    sm += __shfl_xor(sm, m, 64);
                    sq += __shfl_xor(sq, m, 64);
                }
                float mu = sm * 0.015625f;
                float is = rsqrtf(sq * 0.015625f - mu * mu + 1e-5f);
                int row = mt * 16 + l4 * 4 + j;
                int sw  = (row & 7) << 4;
                #pragma unroll
                for (int nt = 0; nt < 4; ++nt) {
                    int col = nt * 16 + l15;
                    *(short*)(syB + row * 128 + ((col * 2) ^ sw)) =
                        (short)hcvt((v[nt] - mu) * is * lgv[nt] + lbv[nt]);
                }
            }
    }

    // cache y1 A-frags from own tile (wave-private; same-wave RAW on LDS is
    // issue-ordered, safe)
    bf16x8 aC2[6];
    #pragma unroll
    for (int ks = 0; ks < 2; ++ks)
        #pragma unroll
        for (int mt = 0; mt < 3; ++mt) {
            int row = mt * 16 + l15;
            int kb  = (ks * 32 + l4 * 8) * 2;
            aC2[ks * 3 + mt] = *(const bf16x8*)(syB + row * 128 + (kb ^ ((row & 7) << 4)));
        }
    __syncthreads();                                       // B7: W2 resident

    // ============ GEMM2 pass S2: y1 @ te1 ============
    #pragma unroll
    for (int mt = 0; mt < 3; ++mt)
        #pragma unroll
        for (int nt = 0; nt < 4; ++nt) acc[mt][nt] = (f32x4)0.f;
    #pragma unroll
    for (int ks = 0; ks < 2; ++ks)
        #pragma unroll
        for (int nt = 0; nt < 4; ++nt) {
            bf16x8 b = ldwb(ks * 8 + nt);
            #pragma unroll
            for (int mt = 0; mt < 3; ++mt)
                acc[mt][nt] = __builtin_amdgcn_mfma_f32_16x16x32_bf16(aC2[ks * 3 + mt], b, acc[mt][nt], 0, 0, 0);
        }
    // s1 = relu(acc) overwrites y1 tile (y1 safe in aC2)
    #pragma unroll
    for (int mt = 0; mt < 3; ++mt)
        #pragma unroll
        for (int j = 0; j < 4; ++j) {
            int row = mt * 16 + l4 * 4 + j;
            int sw  = (row & 7) << 4;
            #pragma unroll
            for (int nt = 0; nt < 4; ++nt) {
                int col = nt * 16 + l15;
                *(short*)(syB + row * 128 + ((col * 2) ^ sw)) =
                    (short)hcvt(fmaxf(acc[mt][nt][j], 0.f));
            }
        }

    // ============ GEMM2 pass R2: y1 @ rw1T ============
    #pragma unroll
    for (int mt = 0; mt < 3; ++mt)
        #pragma unroll
        for (int nt = 0; nt < 4; ++nt) acc[mt][nt] = (f32x4)0.f;
    #pragma unroll
    for (int ks = 0; ks < 2; ++ks)
        #pragma unroll
        for (int nt = 0; nt < 4; ++nt) {
            bf16x8 b = ldwb(ks * 8 + 4 + nt);
            #pragma unroll
            for (int mt = 0; mt < 3; ++mt)
                acc[mt][nt] = __builtin_amdgcn_mfma_f32_16x16x32_bf16(aC2[ks * 3 + mt], b, acc[mt][nt], 0, 0, 0);
        }
    __syncthreads();                                       // B8: done reading W2

    // ============ stage TW1 (24 frags) ============
    #pragma unroll
    for (int i = 0; i < 6; ++i) {
        int sl = i * 4 + wave;
        stage1(sl, FR_TW1 + sl);
    }
    __syncthreads();                                       // B9: TW1 resident

    // ============ tconv1 += acc ============
    #pragma unroll
    for (int dt = 0; dt < 3; ++dt) {
        #pragma unroll
        for (int ks = 0; ks < 2; ++ks) {
            bf16x8 a[3];
            #pragma unroll
            for (int mt = 0; mt < 3; ++mt) {
                int ts    = tA[mt] + dt - 1;
                bool ok   = (ts >= 0) && (ts < 12);
                int srow  = ok ? (mt * 16 + l15 + dt - 1) : (mt * 16 + l15);
                int kb    = (ks * 32 + l4 * 8) * 2;
                bf16x8 av = *(const bf16x8*)(syB + srow * 128 + (kb ^ ((srow & 7) << 4)));
                a[mt] = ok ? av : (bf16x8)(short)0;
            }
            #pragma unroll
            for (int nt = 0; nt < 4; ++nt) {
                bf16x8 b = ldwb(dt * 8 + ks * 4 + nt);
                #pragma unroll
                for (int mt = 0; mt < 3; ++mt)
                    acc[mt][nt] = __builtin_amdgcn_mfma_f32_16x16x32_bf16(a[mt], b, acc[mt][nt], 0, 0, 0);
            }
        }
    }
    __syncthreads();                                       // B10: done reading TW1

    // ============ stage FW (24 frags) — latency hidden under LN1 ============
    #pragma unroll
    for (int i = 0; i < 6; ++i) {
        int sl = i * 4 + wave;
        stage1(sl, FR_FW + sl);
    }

    // ============ bias + relu + LN1 -> y2 back into own tile ============
    {
        float bv[4], lgv[4], lbv[4];
        #pragma unroll
        for (int nt = 0; nt < 4; ++nt) {
            int col = nt * 16 + l15;
            bv[nt]  = rb1[col] + tb1[col];
            lgv[nt] = lg1[col];
            lbv[nt] = lb1[col];
        }
        #pragma unroll
        for (int mt = 0; mt < 3; ++mt)
            #pragma unroll
            for (int j = 0; j < 4; ++j) {
                float v[4], sm = 0.f, sq = 0.f;
                #pragma unroll
                for (int nt = 0; nt < 4; ++nt) {
                    v[nt] = fmaxf(acc[mt][nt][j] + bv[nt], 0.f);
                    sm += v[nt]; sq += v[nt] * v[nt];
                }
                #pragma unroll
                for (int m = 8; m; m >>= 1) {
                    sm += __shfl_xor(sm, m, 64);
                    sq += __shfl_xor(sq, m, 64);
                }
                float mu = sm * 0.015625f;
                float is = rsqrtf(sq * 0.015625f - mu * mu + 1e-5f);
                int row = mt * 16 + l4 * 4 + j;
                int sw  = (row & 7) << 4;
                #pragma unroll
                for (int nt = 0; nt < 4; ++nt) {
                    int col = nt * 16 + l15;
                    *(short*)(syB + row * 128 + ((col * 2) ^ sw)) =
                        (short)hcvt((v[nt] - mu) * is * lgv[nt] + lbv[nt]);
                }
            }
    }
    __syncthreads();                                       // B11: FW resident

    // ============ final: per-wave, A-row = pair (rows >=4 clamped) ============
    // out[p][po] = fb[po] + sum_{k=(t,f)} y2[p][t][f] * FW[k][po]
    {
        f32x4 acc0 = (f32x4)0.f, acc1 = (f32x4)0.f;
        int p   = (l15 < 4) ? l15 : 0;   // clamp pad rows (D rows 4..15 unused)
        #pragma unroll
        for (int ks = 0; ks < 24; ks += 2) {
            {   // even ks
                int t = ks >> 1, f0 = l4 * 8;
                int row = p * 12 + t;
                bf16x8 a = *(const bf16x8*)(syB + row * 128 + ((f0 * 2) ^ ((row & 7) << 4)));
                acc0 = __builtin_amdgcn_mfma_f32_16x16x32_bf16(a, ldwb(ks), acc0, 0, 0, 0);
            }
            {   // odd ks
                int t = ks >> 1, f0 = 32 + l4 * 8;
                int row = p * 12 + t;
                bf16x8 a = *(const bf16x8*)(syB + row * 128 + ((f0 * 2) ^ ((row & 7) << 4)));
                acc1 = __builtin_amdgcn_mfma_f32_16x16x32_bf16(a, ldwb(ks + 1), acc1, 0, 0, 0);
            }
        }
        // D[l4*4+j][l15]: M-row = pair (valid rows 0..3 -> l4==0), col = po
        if (l4 == 0 && l15 < 12) {
            float fbv = fb[l15];
            #pragma unroll
            for (int j = 0; j < 4; ++j)
                out[(long)(pair0 + j) * 12 + l15] = acc0[j] + acc1[j] + fbv;
        }
    }
}

extern "C" void kernel_launch(void* const* d_in, const int* in_sizes, int n_in,
                              void* d_out, int out_size, void* d_ws, size_t ws_size,
                              hipStream_t stream)
{
    (void)in_sizes; (void)n_in; (void)out_size; (void)ws_size;
    const float* x   = (const float*)d_in[0];
    const float* th0 = (const float*)d_in[1];
    const float* tw0 = (const float*)d_in[2];
    const float* tb0 = (const float*)d_in[3];
    const float* rw0 = (const float*)d_in[4];
    const float* rb0 = (const float*)d_in[5];
    const float* lg0 = (const float*)d_in[6];
    const float* lb0 = (const float*)d_in[7];
    const float* th1 = (const float*)d_in[8];
    const float* tw1 = (const float*)d_in[9];
    const float* tb1 = (const float*)d_in[10];
    const float* rw1 = (const float*)d_in[11];
    const float* rb1 = (const float*)d_in[12];
    const float* lg1 = (const float*)d_in[13];
    const float* lb1 = (const float*)d_in[14];
    const float* fw  = (const float*)d_in[15];
    const float* fb  = (const float*)d_in[16];
    float* out = (float*)d_out;
    short* wsb = (short*)d_ws;

    prep<<<240, 256, 0, stream>>>(th0, tw0, rw0, th1, tw1, rw1, fw, wsb);
    mstgcn_mfma<<<1024, 256, 0, stream>>>(x, wsb, tb0, rb0, lg0, lb0,
                                          tb1, rb1, lg1, lb1, fb, out);
}

// Round 12
// 48.981 us; speedup vs baseline: 1.0936x; 1.0936x over previous
//
#include <hip/hip_runtime.h>
#include <hip/hip_bf16.h>

// MSTGCN head — fused bf16-MFMA implementation (round 12 = round 11 + DPP fix).
// cheb = [I,-I,I] (identity adjacency) => graph conv = per-(b,n) GEMM with
// te = theta0 - theta1 + theta2.
//
// Decomposition: 16384 (b,n) pairs. Wave = 4 pairs = 48 rows = 3 M-tiles of 16.
// Block = 4 waves = 16 pairs. Grid = 1024.
//
// Round-12 fix: __builtin_amdgcn_update_dpp requires a LITERAL dpp_ctrl ->
// ctrl moved to a template parameter.
// Round-11 changes under test (DS-pipe-bound theory):
//  - LN 16-lane reductions via DPP (quad_perm xor1/xor2 + row_half_mirror +
//    row_mirror) on the VALU pipe: removes ~192 DS shuffle ops/wave and cuts
//    the per-row reduce latency chain ~10x.
//  - weight staging via __builtin_amdgcn_global_load_lds width=16 (async
//    direct-to-LDS, no ds_write, no VGPR round trip); stages for W2/FW fly
//    under LN0/LN1 and drain at the existing barriers.
// Structure otherwise identical to round 10 (24KB tiles + 24KB phase WB,
// 3 blocks/CU, single-acc two-pass GEMMs, 11 barriers).

typedef __attribute__((ext_vector_type(8))) short bf16x8;
typedef __attribute__((ext_vector_type(4))) float f32x4;

typedef __attribute__((address_space(1))) const unsigned int gu32;
typedef __attribute__((address_space(3))) unsigned int lu32;

#define FR_W1   0     // 32 frags: ks(4)*8 + nt(8)   K=128,N=128 [te0|rw0T]
#define FR_TW0  32    // 24 frags: dt*8 + ks(2)*4 + nt(4)
#define FR_W2   56    // 16 frags: ks(2)*8 + nt(8)   K=64,N=128 [te1|rw1T]
#define FR_TW1  72    // 24 frags
#define FR_FW   96    // 24 frags: ks(24), N=16 (cols 12..15 zero)
#define N_FRAGS 120

__device__ __forceinline__ unsigned short f2bf(float f) {
    unsigned u = __builtin_bit_cast(unsigned, f);
    return (unsigned short)((u + 0x7FFFu + ((u >> 16) & 1u)) >> 16);
}

__device__ __forceinline__ unsigned short hcvt(float f) {
    union { __hip_bfloat16 h; unsigned short u; } cv;
    cv.h = __float2bfloat16(f);
    return cv.u;
}

// 16-lane (DPP row) all-reduce add, pure VALU.
// After xor1+xor2 values are quad-uniform, so half_mirror==xor4, mirror==xor8.
template <int CTRL>
__device__ __forceinline__ float dpp_add(float v) {
    int t = __builtin_amdgcn_update_dpp(0, __builtin_bit_cast(int, v),
                                        CTRL, 0xf, 0xf, true);
    return v + __builtin_bit_cast(float, t);
}
__device__ __forceinline__ float red16(float v) {
    v = dpp_add<0xB1>(v);    // quad_perm [1,0,3,2]  (xor 1)
    v = dpp_add<0x4E>(v);    // quad_perm [2,3,0,1]  (xor 2)
    v = dpp_add<0x141>(v);   // row_half_mirror      (xor 4 effective)
    v = dpp_add<0x140>(v);   // row_mirror           (xor 8 effective)
    return v;
}

__global__ void prep(const float* __restrict__ th0, const float* __restrict__ tw0,
                     const float* __restrict__ rw0, const float* __restrict__ th1,
                     const float* __restrict__ tw1, const float* __restrict__ rw1,
                     const float* __restrict__ fw,  short* __restrict__ wsb)
{
    int e = blockIdx.x * 256 + threadIdx.x;     // (frag, lane, i)
    if (e >= N_FRAGS * 512) return;
    int frag = e >> 9;
    int l    = (e >> 3) & 63;
    int i    = e & 7;
    int kif  = ((l >> 4) << 3) + i;             // k within 32-chunk
    int nif  = l & 15;
    float val = 0.f;
    if (frag < 32) {                                       // W1
        int ks = frag >> 3, nt = frag & 7;
        int k = ks * 32 + kif, n = nt * 16 + nif;
        if (n < 64) val = th0[k*64+n] - th0[8192 + k*64+n] + th0[16384 + k*64+n];
        else        val = rw0[(n - 64) * 128 + k];
    } else if (frag < 56) {                                // TW0
        int q = frag - 32; int dt = q >> 3, ks = (q >> 2) & 1, nt = q & 3;
        int c = ks * 32 + kif, o = nt * 16 + nif;
        val = tw0[o * 192 + c * 3 + dt];
    } else if (frag < 72) {                                // W2
        int q = frag - 56; int ks = q >> 3, nt = q & 7;
        int k = ks * 32 + kif, n = nt * 16 + nif;
        if (n < 64) val = th1[k*64+n] - th1[4096 + k*64+n] + th1[8192 + k*64+n];
        else        val = rw1[(n - 64) * 64 + k];
    } else if (frag < 96) {                                // TW1
        int q = frag - 72; int dt = q >> 3, ks = (q >> 2) & 1, nt = q & 3;
        int c = ks * 32 + kif, o = nt * 16 + nif;
        val = tw1[o * 192 + c * 3 + dt];
    } else {                                               // FW
        int ks = frag - 96; int k = ks * 32 + kif; int po = nif;
        val = (po < 12) ? fw[po * 768 + k] : 0.f;
    }
    wsb[e] = (short)f2bf(val);
}

// LDS layout:
//   [0 .. 24575]   : 4 per-wave 48x64 bf16 s/y tiles (6 KB each, XOR-swizzled)
//   [24576..49151] : 24 KB weight buffer (one phase at a time)
#define LDS_SY(w)  (LDS + (w) * 6144)
#define LDS_WB     (LDS + 24576)

__global__ __launch_bounds__(256, 3) void mstgcn_mfma(
    const float* __restrict__ x,   const short* __restrict__ wsb,
    const float* __restrict__ tb0, const float* __restrict__ rb0,
    const float* __restrict__ lg0, const float* __restrict__ lb0,
    const float* __restrict__ tb1, const float* __restrict__ rb1,
    const float* __restrict__ lg1, const float* __restrict__ lb1,
    const float* __restrict__ fb,  float* __restrict__ out)
{
    __shared__ __align__(16) char LDS[49152];

    const int lane = threadIdx.x & 63;
    const int wave = threadIdx.x >> 6;
    const int l15  = lane & 15;
    const int l4   = lane >> 4;
    const int pair0 = blockIdx.x * 16 + wave * 4;

    char* syB = LDS_SY(wave);
    char* WB  = LDS_WB;

    // WB readers: slot = 1KB fragment, lane-consecutive 16B
    auto ldwb = [&](int slot) -> bf16x8 {
        return *(const bf16x8*)(WB + slot * 1024 + lane * 16);
    };
    // async stage: global frag fg -> WB slot, direct-to-LDS (lane x 16B)
    auto stage1 = [&](int slot, int fg) {
        __builtin_amdgcn_global_load_lds(
            (gu32*)(wsb + fg * 512 + lane * 8),
            (lu32*)(WB + slot * 1024), 16, 0, 0);
    };

    // A-row decode (rows 0..47 within wave; row -> (pair, t))
    int tA[3];
    long gbase[3];
    #pragma unroll
    for (int mt = 0; mt < 3; ++mt) {
        int r = mt * 16 + l15;
        int p = r / 12;
        tA[mt]   = r - p * 12;
        gbase[mt] = ((long)(pair0 + p) * 12 + tA[mt]) * 128;
    }

    // ============ stage W1S (16 frags: ks*8+nt, nt<4) ∥ X->aC prefetch =======
    #pragma unroll
    for (int i = 0; i < 4; ++i) {
        int sl = i * 4 + wave;
        stage1(sl, ((sl >> 2) << 3) + (sl & 3));
    }
    bf16x8 aC[12];
    #pragma unroll
    for (int ks = 0; ks < 4; ++ks)
        #pragma unroll
        for (int mt = 0; mt < 3; ++mt) {
            const float* p = x + gbase[mt] + ks * 32 + l4 * 8;
            float v[8];
            *(float4*)(v)     = *(const float4*)(p);
            *(float4*)(v + 4) = *(const float4*)(p + 4);
            bf16x8 af;
            #pragma unroll
            for (int j = 0; j < 8; ++j) af[j] = (short)hcvt(v[j]);
            aC[ks * 3 + mt] = af;
        }
    __syncthreads();                                       // B1: W1S resident

    f32x4 acc[3][4];
    #pragma unroll
    for (int mt = 0; mt < 3; ++mt)
        #pragma unroll
        for (int nt = 0; nt < 4; ++nt) acc[mt][nt] = (f32x4)0.f;

    // ============ GEMM1 pass S: X @ te0 ============
    #pragma unroll
    for (int ks = 0; ks < 4; ++ks)
        #pragma unroll
        for (int nt = 0; nt < 4; ++nt) {
            bf16x8 b = ldwb(ks * 4 + nt);
            #pragma unroll
            for (int mt = 0; mt < 3; ++mt)
                acc[mt][nt] = __builtin_amdgcn_mfma_f32_16x16x32_bf16(aC[ks * 3 + mt], b, acc[mt][nt], 0, 0, 0);
        }
    // s = relu(acc) -> own tile (swizzled bf16)
    #pragma unroll
    for (int mt = 0; mt < 3; ++mt)
        #pragma unroll
        for (int j = 0; j < 4; ++j) {
            int row = mt * 16 + l4 * 4 + j;
            int sw  = (row & 7) << 4;
            #pragma unroll
            for (int nt = 0; nt < 4; ++nt) {
                int col = nt * 16 + l15;
                *(short*)(syB + row * 128 + ((col * 2) ^ sw)) =
                    (short)hcvt(fmaxf(acc[mt][nt][j], 0.f));
            }
        }
    __syncthreads();                                       // B2: done reading W1S

    // ============ stage W1R (frags ks*8+4+nt) ============
    #pragma unroll
    for (int i = 0; i < 4; ++i) {
        int sl = i * 4 + wave;
        stage1(sl, ((sl >> 2) << 3) + 4 + (sl & 3));
    }
    __syncthreads();                                       // B3: W1R resident

    // ============ GEMM1 pass R: X @ rw0T ============
    #pragma unroll
    for (int mt = 0; mt < 3; ++mt)
        #pragma unroll
        for (int nt = 0; nt < 4; ++nt) acc[mt][nt] = (f32x4)0.f;
    #pragma unroll
    for (int ks = 0; ks < 4; ++ks)
        #pragma unroll
        for (int nt = 0; nt < 4; ++nt) {
            bf16x8 b = ldwb(ks * 4 + nt);
            #pragma unroll
            for (int mt = 0; mt < 3; ++mt)
                acc[mt][nt] = __builtin_amdgcn_mfma_f32_16x16x32_bf16(aC[ks * 3 + mt], b, acc[mt][nt], 0, 0, 0);
        }
    __syncthreads();                                       // B4: done reading W1R

    // ============ stage TW0 (24 frags) ============
    #pragma unroll
    for (int i = 0; i < 6; ++i) {
        int sl = i * 4 + wave;
        stage1(sl, FR_TW0 + sl);
    }
    __syncthreads();                                       // B5: TW0 resident

    // ============ tconv0 (3 shifted GEMMs) += acc ============
    #pragma unroll
    for (int dt = 0; dt < 3; ++dt) {
        #pragma unroll
        for (int ks = 0; ks < 2; ++ks) {
            bf16x8 a[3];
            #pragma unroll
            for (int mt = 0; mt < 3; ++mt) {
                int ts    = tA[mt] + dt - 1;
                bool ok   = (ts >= 0) && (ts < 12);
                int srow  = ok ? (mt * 16 + l15 + dt - 1) : (mt * 16 + l15);
                int kb    = (ks * 32 + l4 * 8) * 2;
                bf16x8 av = *(const bf16x8*)(syB + srow * 128 + (kb ^ ((srow & 7) << 4)));
                a[mt] = ok ? av : (bf16x8)(short)0;
            }
            #pragma unroll
            for (int nt = 0; nt < 4; ++nt) {
                bf16x8 b = ldwb(dt * 8 + ks * 4 + nt);
                #pragma unroll
                for (int mt = 0; mt < 3; ++mt)
                    acc[mt][nt] = __builtin_amdgcn_mfma_f32_16x16x32_bf16(a[mt], b, acc[mt][nt], 0, 0, 0);
            }
        }
    }
    __syncthreads();                                       // B6: done reading TW0

    // ============ stage W2 (16 frags) — async, lands during LN0 ============
    #pragma unroll
    for (int i = 0; i < 4; ++i) {
        int sl = i * 4 + wave;
        stage1(sl, FR_W2 + sl);
    }

    // ============ bias + relu + LN0 -> y1 into own tile ============
    {
        float bv[4], lgv[4], lbv[4];
        #pragma unroll
        for (int nt = 0; nt < 4; ++nt) {
            int col = nt * 16 + l15;
            bv[nt]  = rb0[col] + tb0[col];
            lgv[nt] = lg0[col];
            lbv[nt] = lb0[col];
        }
        #pragma unroll
        for (int mt = 0; mt < 3; ++mt)
            #pragma unroll
            for (int j = 0; j < 4; ++j) {
                float v[4], sm = 0.f, sq = 0.f;
                #pragma unroll
                for (int nt = 0; nt < 4; ++nt) {
                    v[nt] = fmaxf(acc[mt][nt][j] + bv[nt], 0.f);
                    sm += v[nt]; sq += v[nt] * v[nt];
                }
                sm = red16(sm);
                sq = red16(sq);
                float mu = sm * 0.015625f;
                float is = rsqrtf(sq * 0.015625f - mu * mu + 1e-5f);
                int row = mt * 16 + l4 * 4 + j;
                int sw  = (row & 7) << 4;
                #pragma unroll
                for (int nt = 0; nt < 4; ++nt) {
                    int col = nt * 16 + l15;
                    *(short*)(syB + row * 128 + ((col * 2) ^ sw)) =
                        (short)hcvt((v[nt] - mu) * is * lgv[nt] + lbv[nt]);
                }
            }
    }

    // cache y1 A-frags from own tile (wave-private; same-wave RAW on LDS is
    // issue-ordered, safe)
    bf16x8 aC2[6];
    #pragma unroll
    for (int ks = 0; ks < 2; ++ks)
        #pragma unroll
        for (int mt = 0; mt < 3; ++mt) {
            int row = mt * 16 + l15;
            int kb  = (ks * 32 + l4 * 8) * 2;
            aC2[ks * 3 + mt] = *(const bf16x8*)(syB + row * 128 + (kb ^ ((row & 7) << 4)));
        }
    __syncthreads();                                       // B7: W2 resident

    // ============ GEMM2 pass S2: y1 @ te1 ============
    #pragma unroll
    for (int mt = 0; mt < 3; ++mt)
        #pragma unroll
        for (int nt = 0; nt < 4; ++nt) acc[mt][nt] = (f32x4)0.f;
    #pragma unroll
    for (int ks = 0; ks < 2; ++ks)
        #pragma unroll
        for (int nt = 0; nt < 4; ++nt) {
            bf16x8 b = ldwb(ks * 8 + nt);
            #pragma unroll
            for (int mt = 0; mt < 3; ++mt)
                acc[mt][nt] = __builtin_amdgcn_mfma_f32_16x16x32_bf16(aC2[ks * 3 + mt], b, acc[mt][nt], 0, 0, 0);
        }
    // s1 = relu(acc) overwrites y1 tile (y1 safe in aC2)
    #pragma unroll
    for (int mt = 0; mt < 3; ++mt)
        #pragma unroll
        for (int j = 0; j < 4; ++j) {
            int row = mt * 16 + l4 * 4 + j;
            int sw  = (row & 7) << 4;
            #pragma unroll
            for (int nt = 0; nt < 4; ++nt) {
                int col = nt * 16 + l15;
                *(short*)(syB + row * 128 + ((col * 2) ^ sw)) =
                    (short)hcvt(fmaxf(acc[mt][nt][j], 0.f));
            }
        }

    // ============ GEMM2 pass R2: y1 @ rw1T ============
    #pragma unroll
    for (int mt = 0; mt < 3; ++mt)
        #pragma unroll
        for (int nt = 0; nt < 4; ++nt) acc[mt][nt] = (f32x4)0.f;
    #pragma unroll
    for (int ks = 0; ks < 2; ++ks)
        #pragma unroll
        for (int nt = 0; nt < 4; ++nt) {
            bf16x8 b = ldwb(ks * 8 + 4 + nt);
            #pragma unroll
            for (int mt = 0; mt < 3; ++mt)
                acc[mt][nt] = __builtin_amdgcn_mfma_f32_16x16x32_bf16(aC2[ks * 3 + mt], b, acc[mt][nt], 0, 0, 0);
        }
    __syncthreads();                                       // B8: done reading W2

    // ============ stage TW1 (24 frags) ============
    #pragma unroll
    for (int i = 0; i < 6; ++i) {
        int sl = i * 4 + wave;
        stage1(sl, FR_TW1 + sl);
    }
    __syncthreads();                                       // B9: TW1 resident

    // ============ tconv1 += acc ============
    #pragma unroll
    for (int dt = 0; dt < 3; ++dt) {
        #pragma unroll
        for (int ks = 0; ks < 2; ++ks) {
            bf16x8 a[3];
            #pragma unroll
            for (int mt = 0; mt < 3; ++mt) {
                int ts    = tA[mt] + dt - 1;
                bool ok   = (ts >= 0) && (ts < 12);
                int srow  = ok ? (mt * 16 + l15 + dt - 1) : (mt * 16 + l15);
                int kb    = (ks * 32 + l4 * 8) * 2;
                bf16x8 av = *(const bf16x8*)(syB + srow * 128 + (kb ^ ((srow & 7) << 4)));
                a[mt] = ok ? av : (bf16x8)(short)0;
            }
            #pragma unroll
            for (int nt = 0; nt < 4; ++nt) {
                bf16x8 b = ldwb(dt * 8 + ks * 4 + nt);
                #pragma unroll
                for (int mt = 0; mt < 3; ++mt)
                    acc[mt][nt] = __builtin_amdgcn_mfma_f32_16x16x32_bf16(a[mt], b, acc[mt][nt], 0, 0, 0);
            }
        }
    }
    __syncthreads();                                       // B10: done reading TW1

    // ============ stage FW (24 frags) — async, lands during LN1 ============
    #pragma unroll
    for (int i = 0; i < 6; ++i) {
        int sl = i * 4 + wave;
        stage1(sl, FR_FW + sl);
    }

    // ============ bias + relu + LN1 -> y2 back into own tile ============
    {
        float bv[4], lgv[4], lbv[4];
        #pragma unroll
        for (int nt = 0; nt < 4; ++nt) {
            int col = nt * 16 + l15;
            bv[nt]  = rb1[col] + tb1[col];
            lgv[nt] = lg1[col];
            lbv[nt] = lb1[col];
        }
        #pragma unroll
        for (int mt = 0; mt < 3; ++mt)
            #pragma unroll
            for (int j = 0; j < 4; ++j) {
                float v[4], sm = 0.f, sq = 0.f;
                #pragma unroll
                for (int nt = 0; nt < 4; ++nt) {
                    v[nt] = fmaxf(acc[mt][nt][j] + bv[nt], 0.f);
                    sm += v[nt]; sq += v[nt] * v[nt];
                }
                sm = red16(sm);
                sq = red16(sq);
                float mu = sm * 0.015625f;
                float is = rsqrtf(sq * 0.015625f - mu * mu + 1e-5f);
                int row = mt * 16 + l4 * 4 + j;
                int sw  = (row & 7) << 4;
                #pragma unroll
                for (int nt = 0; nt < 4; ++nt) {
                    int col = nt * 16 + l15;
                    *(short*)(syB + row * 128 + ((col * 2) ^ sw)) =
                        (short)hcvt((v[nt] - mu) * is * lgv[nt] + lbv[nt]);
                }
            }
    }
    __syncthreads();                                       // B11: FW resident

    // ============ final: per-wave, A-row = pair (rows >=4 clamped) ============
    // out[p][po] = fb[po] + sum_{k=(t,f)} y2[p][t][f] * FW[k][po]
    {
        f32x4 acc0 = (f32x4)0.f, acc1 = (f32x4)0.f;
        int p   = (l15 < 4) ? l15 : 0;   // clamp pad rows (D rows 4..15 unused)
        #pragma unroll
        for (int ks = 0; ks < 24; ks += 2) {
            {   // even ks
                int t = ks >> 1, f0 = l4 * 8;
                int row = p * 12 + t;
                bf16x8 a = *(const bf16x8*)(syB + row * 128 + ((f0 * 2) ^ ((row & 7) << 4)));
                acc0 = __builtin_amdgcn_mfma_f32_16x16x32_bf16(a, ldwb(ks), acc0, 0, 0, 0);
            }
            {   // odd ks
                int t = ks >> 1, f0 = 32 + l4 * 8;
                int row = p * 12 + t;
                bf16x8 a = *(const bf16x8*)(syB + row * 128 + ((f0 * 2) ^ ((row & 7) << 4)));
                acc1 = __builtin_amdgcn_mfma_f32_16x16x32_bf16(a, ldwb(ks + 1), acc1, 0, 0, 0);
            }
        }
        // D[l4*4+j][l15]: M-row = pair (valid rows 0..3 -> l4==0), col = po
        if (l4 == 0 && l15 < 12) {
            float fbv = fb[l15];
            #pragma unroll
            for (int j = 0; j < 4; ++j)
                out[(long)(pair0 + j) * 12 + l15] = acc0[j] + acc1[j] + fbv;
        }
    }
}

extern "C" void kernel_launch(void* const* d_in, const int* in_sizes, int n_in,
                              void* d_out, int out_size, void* d_ws, size_t ws_size,
                              hipStream_t stream)
{
    (void)in_sizes; (void)n_in; (void)out_size; (void)ws_size;
    const float* x   = (const float*)d_in[0];
    const float* th0 = (const float*)d_in[1];
    const float* tw0 = (const float*)d_in[2];
    const float* tb0 = (const float*)d_in[3];
    const float* rw0 = (const float*)d_in[4];
    const float* rb0 = (const float*)d_in[5];
    const float* lg0 = (const float*)d_in[6];
    const float* lb0 = (const float*)d_in[7];
    const float* th1 = (const float*)d_in[8];
    const float* tw1 = (const float*)d_in[9];
    const float* tb1 = (const float*)d_in[10];
    const float* rw1 = (const float*)d_in[11];
    const float* rb1 = (const float*)d_in[12];
    const float* lg1 = (const float*)d_in[13];
    const float* lb1 = (const float*)d_in[14];
    const float* fw  = (const float*)d_in[15];
    const float* fb  = (const float*)d_in[16];
    float* out = (float*)d_out;
    short* wsb = (short*)d_ws;

    prep<<<240, 256, 0, stream>>>(th0, tw0, rw0, th1, tw1, rw1, fw, wsb);
    mstgcn_mfma<<<1024, 256, 0, stream>>>(x, wsb, tb0, rb0, lg0, lb0,
                                          tb1, rb1, lg1, lb1, fb, out);
}